// Round 1
// baseline (1397.143 us; speedup 1.0000x reference)
//
#include <hip/hip_runtime.h>
#include <cfloat>
#include <math.h>

// VectorKNN: query (1,256) fp32, bank (1e6,256) fp32, k=5.
// out (float*): [0..4] = top idx (as float, exact < 2^24), [5..9] = top vals.
//
// Pass 1: wave-per-row dot products (lane i loads float4 -> 64*16B = one 1KB row
//         per wave-load, perfectly coalesced). Per-wave register top-5.
// Pass 2: single block merges 4096*5 candidates, applies 1/max(||q||,eps).

#define D 256
#define TPB 256
#define NBLOCKS 1024
#define WAVES_PER_BLOCK (TPB / 64)
#define NWAVES (NBLOCKS * WAVES_PER_BLOCK) // 4096
#define KSEL 5

__device__ __forceinline__ float wave_sum(float v) {
    #pragma unroll
    for (int o = 32; o > 0; o >>= 1) v += __shfl_xor(v, o, 64);
    return v;
}

__device__ __forceinline__ void top5_insert(float (&bv)[KSEL], int (&bi)[KSEL],
                                            float d, int row) {
    if (d > bv[KSEL - 1]) {            // wave-uniform (d is post-butterfly)
        int j = KSEL - 1;
        while (j > 0 && d > bv[j - 1]) {  // strict > : ties keep earlier (lower) idx
            bv[j] = bv[j - 1]; bi[j] = bi[j - 1]; --j;
        }
        bv[j] = d; bi[j] = row;
    }
}

__global__ __launch_bounds__(TPB) void knn_dots(
        const float* __restrict__ q, const float* __restrict__ bank, int n,
        float* __restrict__ cand_val, int* __restrict__ cand_idx) {
    const int lane = threadIdx.x & 63;
    const int wave = (blockIdx.x * TPB + threadIdx.x) >> 6;

    const float4 q4 = reinterpret_cast<const float4*>(q)[lane];

    const int rpw   = (n + NWAVES - 1) / NWAVES;
    const int start = wave * rpw;
    const int end   = min(start + rpw, n);

    float bv[KSEL]; int bi[KSEL];
    #pragma unroll
    for (int j = 0; j < KSEL; ++j) { bv[j] = -FLT_MAX; bi[j] = 0; }

    int row = start;
    for (; row + 4 <= end; row += 4) {
        const float4* r0 = reinterpret_cast<const float4*>(bank + (size_t)(row + 0) * D);
        const float4* r1 = reinterpret_cast<const float4*>(bank + (size_t)(row + 1) * D);
        const float4* r2 = reinterpret_cast<const float4*>(bank + (size_t)(row + 2) * D);
        const float4* r3 = reinterpret_cast<const float4*>(bank + (size_t)(row + 3) * D);
        float4 a0 = r0[lane], a1 = r1[lane], a2 = r2[lane], a3 = r3[lane];

        float d0 = a0.x * q4.x + a0.y * q4.y + a0.z * q4.z + a0.w * q4.w;
        float d1 = a1.x * q4.x + a1.y * q4.y + a1.z * q4.z + a1.w * q4.w;
        float d2 = a2.x * q4.x + a2.y * q4.y + a2.z * q4.z + a2.w * q4.w;
        float d3 = a3.x * q4.x + a3.y * q4.y + a3.z * q4.z + a3.w * q4.w;

        #pragma unroll
        for (int o = 32; o > 0; o >>= 1) {   // interleaved butterflies for ILP
            d0 += __shfl_xor(d0, o, 64);
            d1 += __shfl_xor(d1, o, 64);
            d2 += __shfl_xor(d2, o, 64);
            d3 += __shfl_xor(d3, o, 64);
        }

        top5_insert(bv, bi, d0, row + 0);
        top5_insert(bv, bi, d1, row + 1);
        top5_insert(bv, bi, d2, row + 2);
        top5_insert(bv, bi, d3, row + 3);
    }
    for (; row < end; ++row) {
        const float4* r = reinterpret_cast<const float4*>(bank + (size_t)row * D);
        float4 a = r[lane];
        float d = a.x * q4.x + a.y * q4.y + a.z * q4.z + a.w * q4.w;
        d = wave_sum(d);
        top5_insert(bv, bi, d, row);
    }

    if (lane == 0) {
        #pragma unroll
        for (int j = 0; j < KSEL; ++j) {
            cand_val[wave * KSEL + j] = bv[j];
            cand_idx[wave * KSEL + j] = bi[j];
        }
    }
}

__global__ __launch_bounds__(TPB) void knn_select(
        const float* __restrict__ q,
        const float* __restrict__ cand_val, const int* __restrict__ cand_idx,
        float* __restrict__ out) {
    __shared__ float svals[TPB];
    __shared__ int   sidx[TPB];
    __shared__ int   spos[TPB];
    __shared__ int   selpos[KSEL];
    __shared__ int   selidx[KSEL];
    __shared__ float selval[KSEL];
    __shared__ float snorm;

    const int t = threadIdx.x;

    // ||q||: TPB == D == 256, one element per thread
    float x = q[t];
    svals[t] = x * x;
    __syncthreads();
    for (int s = 128; s > 0; s >>= 1) {
        if (t < s) svals[t] += svals[t + s];
        __syncthreads();
    }
    if (t == 0) snorm = sqrtf(svals[0]);
    __syncthreads();

    const int C = NWAVES * KSEL;
    for (int r = 0; r < KSEL; ++r) {
        float best = -FLT_MAX; int bidx = 0x7fffffff; int bpos = -1;
        for (int p = t; p < C; p += TPB) {
            bool skip = false;
            for (int j = 0; j < r; ++j) skip |= (selpos[j] == p);
            if (skip) continue;
            float v = cand_val[p];
            int  ix = cand_idx[p];
            if (v > best || (v == best && ix < bidx)) { best = v; bidx = ix; bpos = p; }
        }
        svals[t] = best; sidx[t] = bidx; spos[t] = bpos;
        __syncthreads();
        for (int s = 128; s > 0; s >>= 1) {
            if (t < s) {
                bool take = (svals[t + s] > svals[t]) ||
                            (svals[t + s] == svals[t] && sidx[t + s] < sidx[t]);
                if (take) { svals[t] = svals[t + s]; sidx[t] = sidx[t + s]; spos[t] = spos[t + s]; }
            }
            __syncthreads();
        }
        if (t == 0) { selpos[r] = spos[0]; selidx[r] = sidx[0]; selval[r] = svals[0]; }
        __syncthreads();
    }

    if (t == 0) {
        float inv = 1.0f / fmaxf(snorm, 1e-12f);
        #pragma unroll
        for (int j = 0; j < KSEL; ++j) {
            out[j]        = (float)selidx[j];   // exact for idx < 2^24
            out[KSEL + j] = selval[j] * inv;
        }
    }
}

extern "C" void kernel_launch(void* const* d_in, const int* in_sizes, int n_in,
                              void* d_out, int out_size, void* d_ws, size_t ws_size,
                              hipStream_t stream) {
    const float* q    = (const float*)d_in[0];
    const float* bank = (const float*)d_in[1];
    const int n = in_sizes[1] / D;   // 1,000,000

    float* cand_val = (float*)d_ws;                  // NWAVES*KSEL floats (80 KB)
    int*   cand_idx = (int*)(cand_val + NWAVES * KSEL); // NWAVES*KSEL ints (80 KB)
    float* out = (float*)d_out;

    knn_dots<<<NBLOCKS, TPB, 0, stream>>>(q, bank, n, cand_val, cand_idx);
    knn_select<<<1, TPB, 0, stream>>>(q, cand_val, cand_idx, out);
}

// Round 2
// 1369.256 us; speedup vs baseline: 1.0204x; 1.0204x over previous
//
#include <hip/hip_runtime.h>
#include <cfloat>
#include <limits.h>
#include <math.h>

// VectorKNN: query (1,256) fp32, bank (1e6,256) fp32, k=5 cosine top-k.
// out (float*): [0..4] = top idx (as float, exact < 2^24), [5..9] = top vals.
//
// Pass 1 (knn_dots): wave-per-row dots. Lane i loads row[i*4..i*4+3] as float4
//   -> 64 lanes x 16B = one contiguous 1KB row per wave-load (perfect coalesce).
//   4 rows per iteration share one address register (offsets 1024/2048/3072).
//   Pairwise butterfly: 10 shfl + 4 broadcasts per 4 rows (vs 24 naive).
//   Per-wave register top-5 (wave-uniform insert), written to d_ws.
// Pass 2 (knn_select): 1 block. Per-thread single-scan top-5 over strided slice
//   -> LDS -> one wave tree-merge via shfl_down -> lane 0 writes, applying
//   1/max(||q||,eps). Normalization deferred to the final 5 values (argsort
//   is invariant to the positive scale).

#define D 256
#define TPB 256
#define NBLOCKS 2048
#define NWAVES (NBLOCKS * (TPB / 64))   // 8192
#define KSEL 5
#define NCAND (NWAVES * KSEL)           // 40960

__device__ __forceinline__ float wave_sum(float v) {
    #pragma unroll
    for (int o = 32; o > 0; o >>= 1) v += __shfl_xor(v, o, 64);
    return v;
}

// Wave-uniform top-5 insert (d is identical across lanes). Strict '>' keeps
// the earlier (lower) row on ties, matching top_k's lower-index preference.
__device__ __forceinline__ void top5_insert(float (&bv)[KSEL], int (&bi)[KSEL],
                                            float d, int row) {
    if (d > bv[KSEL - 1]) {
        int j = KSEL - 1;
        while (j > 0 && d > bv[j - 1]) {
            bv[j] = bv[j - 1]; bi[j] = bi[j - 1]; --j;
        }
        bv[j] = d; bi[j] = row;
    }
}

__global__ __launch_bounds__(TPB) void knn_dots(
        const float* __restrict__ q, const float* __restrict__ bank, int n,
        float* __restrict__ cand_val, int* __restrict__ cand_idx) {
    const int lane = threadIdx.x & 63;
    const int wave = (blockIdx.x * TPB + threadIdx.x) >> 6;

    const float4 q4 = reinterpret_cast<const float4*>(q)[lane];
    const float4* __restrict__ b4 = reinterpret_cast<const float4*>(bank);

    const int rpw   = (n + NWAVES - 1) / NWAVES;
    const int start = wave * rpw;
    const int end   = min(start + rpw, n);

    float bv[KSEL]; int bi[KSEL];
    #pragma unroll
    for (int j = 0; j < KSEL; ++j) { bv[j] = -FLT_MAX; bi[j] = 0; }

    int row = start;
    for (; row + 4 <= end; row += 4) {
        // one base, immediate offsets (64/128/192 float4 = 1/2/3 KB)
        const float4* base = b4 + (size_t)row * (D / 4) + lane;
        float4 a0 = base[0];
        float4 a1 = base[64];
        float4 a2 = base[128];
        float4 a3 = base[192];

        float d0 = fmaf(a0.x, q4.x, fmaf(a0.y, q4.y, fmaf(a0.z, q4.z, a0.w * q4.w)));
        float d1 = fmaf(a1.x, q4.x, fmaf(a1.y, q4.y, fmaf(a1.z, q4.z, a1.w * q4.w)));
        float d2 = fmaf(a2.x, q4.x, fmaf(a2.y, q4.y, fmaf(a2.z, q4.z, a2.w * q4.w)));
        float d3 = fmaf(a3.x, q4.x, fmaf(a3.y, q4.y, fmaf(a3.z, q4.z, a3.w * q4.w)));

        // pairwise butterfly: 10 shfl for 4 rows
        d0 += __shfl_xor(d0, 32, 64);
        d1 += __shfl_xor(d1, 32, 64);
        d2 += __shfl_xor(d2, 32, 64);
        d3 += __shfl_xor(d3, 32, 64);
        float e01 = (lane & 32) ? d1 : d0;   // halves: [d0 | d1]
        float e23 = (lane & 32) ? d3 : d2;   // halves: [d2 | d3]
        e01 += __shfl_xor(e01, 16, 64);
        e23 += __shfl_xor(e23, 16, 64);
        float f = (lane & 16) ? e23 : e01;   // quarters: [d0 | d2 | d1 | d3]
        #pragma unroll
        for (int o = 8; o > 0; o >>= 1) f += __shfl_xor(f, o, 64);

        float s0 = __shfl(f, 0, 64);
        float s2 = __shfl(f, 16, 64);
        float s1 = __shfl(f, 32, 64);
        float s3 = __shfl(f, 48, 64);

        top5_insert(bv, bi, s0, row + 0);
        top5_insert(bv, bi, s1, row + 1);
        top5_insert(bv, bi, s2, row + 2);
        top5_insert(bv, bi, s3, row + 3);
    }
    for (; row < end; ++row) {
        float4 a = b4[(size_t)row * (D / 4) + lane];
        float d = fmaf(a.x, q4.x, fmaf(a.y, q4.y, fmaf(a.z, q4.z, a.w * q4.w)));
        d = wave_sum(d);
        top5_insert(bv, bi, d, row);
    }

    if (lane == 0) {
        #pragma unroll
        for (int j = 0; j < KSEL; ++j) {
            cand_val[wave * KSEL + j] = bv[j];
            cand_idx[wave * KSEL + j] = bi[j];
        }
    }
}

// (value, index) preference: higher value, then lower index.
__device__ __forceinline__ bool better(float v, int ix, float bv, int bi) {
    return (v > bv) || (v == bv && ix < bi);
}

__device__ __forceinline__ void top5_insert_ti(float (&bv)[KSEL], int (&bi)[KSEL],
                                               float v, int ix) {
    if (better(v, ix, bv[KSEL - 1], bi[KSEL - 1])) {
        int j = KSEL - 1;
        while (j > 0 && better(v, ix, bv[j - 1], bi[j - 1])) {
            bv[j] = bv[j - 1]; bi[j] = bi[j - 1]; --j;
        }
        bv[j] = v; bi[j] = ix;
    }
}

__global__ __launch_bounds__(TPB) void knn_select(
        const float* __restrict__ q,
        const float* __restrict__ cand_val, const int* __restrict__ cand_idx,
        float* __restrict__ out) {
    __shared__ float lv[TPB * KSEL];
    __shared__ int   li[TPB * KSEL];
    __shared__ float wsum[TPB / 64];

    const int t = threadIdx.x;
    const int lane = t & 63;

    // ||q||^2: one element per thread (TPB == D), wave reduce -> LDS
    float x = q[t];
    float xx = x * x;
    #pragma unroll
    for (int o = 32; o > 0; o >>= 1) xx += __shfl_xor(xx, o, 64);
    if (lane == 0) wsum[t >> 6] = xx;

    // per-thread top-5 over strided slice of candidates (single scan)
    float bv[KSEL]; int bi[KSEL];
    #pragma unroll
    for (int j = 0; j < KSEL; ++j) { bv[j] = -FLT_MAX; bi[j] = INT_MAX; }
    for (int p = t; p < NCAND; p += TPB) {
        float v = cand_val[p];
        int  ix = cand_idx[p];
        top5_insert_ti(bv, bi, v, ix);
    }
    #pragma unroll
    for (int j = 0; j < KSEL; ++j) { lv[t * KSEL + j] = bv[j]; li[t * KSEL + j] = bi[j]; }
    __syncthreads();

    if (t < 64) {
        // each lane merges 4 threads' lists (20 entries) from LDS
        #pragma unroll
        for (int j = 0; j < KSEL; ++j) { bv[j] = -FLT_MAX; bi[j] = INT_MAX; }
        const int base = t * 4 * KSEL;
        for (int p = 0; p < 4 * KSEL; ++p)
            top5_insert_ti(bv, bi, lv[base + p], li[base + p]);

        // tree merge: lanes < o absorb lane+o (disjoint sets -> no duplicates)
        #pragma unroll
        for (int o = 32; o > 0; o >>= 1) {
            float ov[KSEL]; int oi[KSEL];
            #pragma unroll
            for (int j = 0; j < KSEL; ++j) {
                ov[j] = __shfl_down(bv[j], o, 64);
                oi[j] = __shfl_down(bi[j], o, 64);
            }
            if (t < o) {
                #pragma unroll
                for (int j = 0; j < KSEL; ++j) top5_insert_ti(bv, bi, ov[j], oi[j]);
            }
        }

        if (t == 0) {
            float nrm = sqrtf(wsum[0] + wsum[1] + wsum[2] + wsum[3]);
            float inv = 1.0f / fmaxf(nrm, 1e-12f);
            #pragma unroll
            for (int j = 0; j < KSEL; ++j) {
                out[j]        = (float)bi[j];     // exact: idx < 2^24
                out[KSEL + j] = bv[j] * inv;
            }
        }
    }
}

extern "C" void kernel_launch(void* const* d_in, const int* in_sizes, int n_in,
                              void* d_out, int out_size, void* d_ws, size_t ws_size,
                              hipStream_t stream) {
    const float* q    = (const float*)d_in[0];
    const float* bank = (const float*)d_in[1];
    const int n = in_sizes[1] / D;   // 1,000,000

    float* cand_val = (float*)d_ws;                       // NCAND floats (160 KB)
    int*   cand_idx = (int*)(cand_val + NCAND);           // NCAND ints   (160 KB)
    float* out = (float*)d_out;

    knn_dots<<<NBLOCKS, TPB, 0, stream>>>(q, bank, n, cand_val, cand_idx);
    knn_select<<<1, TPB, 0, stream>>>(q, cand_val, cand_idx, out);
}